// Round 11
// baseline (156.604 us; speedup 1.0000x reference)
//
#include <hip/hip_runtime.h>
#include <hip/hip_bf16.h>

#define NF 256
#define HW (512 * 512)
#define NIMG 4
// LUT grid: 33^3 nodes, spacing 1/32; cells 32^3, one 64B slot per cell
#define G1 33
#define G2 (33 * 33)        // 1089
#define NPTS (33 * 33 * 33) // 35937
#define GSCALE 32
#define NCELL (32 * 32 * 32) // 32768
#define BMB 32               // build tile (points per block)
#define NBUILD ((NPTS + BMB - 1) / BMB) // 1124

typedef unsigned short u16;
typedef unsigned int u32;
typedef __attribute__((ext_vector_type(8))) short bf16x8v; // 8 bf16 in 4 VGPRs
typedef __attribute__((ext_vector_type(4))) float f32x4;
typedef __attribute__((ext_vector_type(4))) unsigned int u32x4;
typedef __attribute__((ext_vector_type(2))) unsigned int u32x2;

// round-to-nearest-even f32 -> bf16 (prep only)
__device__ __forceinline__ u16 f2bf(float f) {
    union { float f; unsigned u; } v; v.f = f;
    unsigned u = v.u;
    return (u16)((u + 0x7fffu + ((u >> 16) & 1u)) >> 16);
}

// packed f32x2 -> bf16x2 (RNE), single VALU instr; lo -> low16, hi -> high16
__device__ __forceinline__ u32 cvt_pk(float lo, float hi) {
    u32 r;
    asm("v_cvt_pk_bf16_f32 %0, %1, %2" : "=v"(r) : "v"(lo), "v"(hi));
    return r;
}

// unpack bf16 halves of u32
__device__ __forceinline__ float bflo(u32 w) {
    union { u32 u; float f; } v; v.u = w << 16; return v.f;
}
__device__ __forceinline__ float bfhi(u32 w) {
    union { u32 u; float f; } v; v.u = w & 0xffff0000u; return v.f;
}

// tanh(x) = 1 - 2/(e^2x + 1)
__device__ __forceinline__ float tanh_fast(float x) {
    float e = __builtin_amdgcn_exp2f(x * 2.8853900817779268f);
    return fmaf(-2.0f, __builtin_amdgcn_rcpf(e + 1.0f), 1.0f);
}

// LDS swizzle on activation tile A[pts][256 feats] bf16 (rows 512B apart
// = bank-0 aligned): XOR row-low bits into the 16B slot index.
#define SWZ(p, j) ((p) * NF + ((j) ^ (((p) & 7) << 3)))

// Weight fragment layout (coalesced): for layer L, wave-slice w, ks, mi:
//   frag[lane][e]  (64 lanes x 8 bf16 = 1KB contiguous)
//   lane l = 16h + lr holds row (w*64 + mi*16 + lr), k = ks*32 + h*8 + e.
// flat idx = ((((L*4 + w)*8 + ks)*4 + mi)*64 + l)*8 + e
#define WSLICE_STRIDE (8 * 4 * 64 * 8) // 16384 elems per (L,w)

// ---------------------------------------------------------------------------
// prep: fold style into b0; emit fragment-ordered bf16 Wt (3 layers) and W4t.
// ---------------------------------------------------------------------------
__global__ void __launch_bounds__(256)
prep_kernel(const float* __restrict__ W0, const float* __restrict__ b0,
            const float* __restrict__ style,
            const float* __restrict__ W1, const float* __restrict__ W2,
            const float* __restrict__ W3, const float* __restrict__ W4,
            u16* __restrict__ Wt, u16* __restrict__ W4t,
            float* __restrict__ b0f)
{
    int t = blockIdx.x * 256 + threadIdx.x;
    if (t < 3 * NF * NF) {
        int e  = t & 7;
        int l  = (t >> 3) & 63;
        int mi = (t >> 9) & 3;
        int ks = (t >> 11) & 7;
        int w  = (t >> 14) & 3;
        int L  = t >> 16;
        const float* W = (L == 0) ? W1 : (L == 1) ? W2 : W3;
        int row = w * 64 + mi * 16 + (l & 15);
        int k   = ks * 32 + (l >> 4) * 8 + e;
        Wt[t] = f2bf(W[k * NF + row]);
    } else if (t < 3 * NF * NF + 16 * NF) {
        int r  = t - 3 * NF * NF;      // 4096 elems: [ks][lane][e]
        int e  = r & 7;
        int l  = (r >> 3) & 63;
        int ks = r >> 9;
        int row = l & 15;              // output channel (0..2) or zero-pad
        int k   = ks * 32 + (l >> 4) * 8 + e;
        W4t[r] = (row < 3) ? f2bf(W4[k * 3 + row]) : (u16)0;
    } else if (t < 3 * NF * NF + 16 * NF + NF) {
        int j = t - (3 * NF * NF + 16 * NF);
        b0f[j] = b0[j] + style[0] * W0[3 * NF + j]
                       + style[1] * W0[4 * NF + j]
                       + style[2] * W0[5 * NF + j];
    }
}

// ---------------------------------------------------------------------------
// layer 0 (3 -> 256, relu) for one 16-point half of the 32-point tile.
// Thread (p = half*16 + (tid&15), fg = tid>>4) computes feats [16fg,16fg+16).
// ---------------------------------------------------------------------------
__device__ __forceinline__ void layer0_half(u16* __restrict__ A, int gbase,
                                            const float* __restrict__ W0,
                                            const float* __restrict__ b0f,
                                            int tid, int half)
{
    const int p = half * 16 + (tid & 15);
    const int g = gbase + p;
    const int gi = g / G2;
    const int rem = g - gi * G2;
    const int gj = rem / G1;
    const int gk = rem - gj * G1;
    const float x0 = (float)gi * (1.0f / GSCALE);
    const float x1 = (float)gj * (1.0f / GSCALE);
    const float x2 = (float)gk * (1.0f / GSCALE);
    const int fg = tid >> 4; // 0..15
#pragma unroll
    for (int t8 = 0; t8 < 2; ++t8) {
        const int j0 = fg * 16 + t8 * 8;
        u32 pk[4];
#pragma unroll
        for (int jj = 0; jj < 8; jj += 2) {
            int j = j0 + jj;
            float va = fmaf(x0, W0[j],     fmaf(x1, W0[NF + j],     fmaf(x2, W0[2 * NF + j],     b0f[j])));
            float vb = fmaf(x0, W0[j + 1], fmaf(x1, W0[NF + j + 1], fmaf(x2, W0[2 * NF + j + 1], b0f[j + 1])));
            pk[jj >> 1] = cvt_pk(fmaxf(va, 0.f), fmaxf(vb, 0.f));
        }
        *(u32x4*)&A[SWZ(p, j0)] = (u32x4){pk[0], pk[1], pk[2], pk[3]};
    }
}

// ---------------------------------------------------------------------------
// pipeline phase (BMB=32): MFMA (64-feat slice, bias in C-init) over 16-point
// half hm into accM[4], interleaved with tanh-epilogue of accE into half he.
// Safety: M reads rows of half hm; E writes rows of half he; hm != he.
// ---------------------------------------------------------------------------
template<int DOM, int DOE>
__device__ __forceinline__ void phase(u16* __restrict__ A,
                                      const u16* __restrict__ Wsl,
                                      const float* __restrict__ bias,
                                      f32x4 accM[4], f32x4 accE[4],
                                      int hm, int he, int lane, int wave)
{
    const int lr = lane & 15;
    const int h  = lane >> 4;

    if (DOM) {
        const int j0b = wave * 64 + h * 4;
#pragma unroll
        for (int mi = 0; mi < 4; ++mi)
            accM[mi] = *(const f32x4*)&bias[j0b + mi * 16]; // bias -> C-init
    }

#pragma unroll
    for (int ks = 0; ks < 8; ++ks) {
        if (DOM) {
            const int kb = ks * 32 + h * 8;
            bf16x8v w[4], act;
#pragma unroll
            for (int mi = 0; mi < 4; ++mi)
                w[mi] = *(const bf16x8v*)(Wsl + ((ks * 4 + mi) * 64 + lane) * 8);
            {
                int p = hm * 16 + lr;
                act = *(const bf16x8v*)&A[p * NF + (kb ^ ((p & 7) << 3))];
            }
#pragma unroll
            for (int mi = 0; mi < 4; ++mi)
                accM[mi] = __builtin_amdgcn_mfma_f32_16x16x32_bf16(
                    w[mi], act, accM[mi], 0, 0, 0);
        }
        if (DOE) {
            // one epilogue unit per 2 ks steps: 4 units = mi 0..3
            if ((ks & 1) == 0) {
                const int mi = ks >> 1;
                const int p  = he * 16 + lr;
                const int j0 = wave * 64 + mi * 16 + h * 4;
                f32x4 v = accE[mi]; // bias already inside
                float t0 = tanh_fast(v[0]), t1 = tanh_fast(v[1]);
                float t2 = tanh_fast(v[2]), t3 = tanh_fast(v[3]);
                u32x2 pk = (u32x2){cvt_pk(t0, t1), cvt_pk(t2, t3)};
                *(u32x2*)&A[SWZ(p, j0)] = pk;
            }
        }
    }
}

// ---------------------------------------------------------------------------
// LUT build: evaluate MLP residual at 33^3 grid points. 32-point tile,
// 16 KB LDS, VGPR<=64 -> 8 blocks/CU = 32 waves/CU; 1124 blocks -> deep
// per-CU overlap to hide block latency.
// ---------------------------------------------------------------------------
__global__ void __launch_bounds__(256, 8)
build_kernel(const float* __restrict__ W0,
             const float* __restrict__ b1, const float* __restrict__ b2,
             const float* __restrict__ b3, const float* __restrict__ b4,
             const u16* __restrict__ Wt, const u16* __restrict__ W4t,
             const float* __restrict__ b0f, f32x4* __restrict__ lut)
{
    __shared__ __align__(16) u16 A[BMB * NF]; // 16 KB

    const int tid   = threadIdx.x;
    const int lane  = tid & 63;
    const int wave  = tid >> 6;
    const int gbase = blockIdx.x * BMB;

    const u16* Wsl0 = Wt + wave * WSLICE_STRIDE;
    const u16* Wsl1 = Wsl0 + 4 * WSLICE_STRIDE;
    const u16* Wsl2 = Wsl0 + 8 * WSLICE_STRIDE;

    f32x4 accA[4], accB[4];

    layer0_half(A, gbase, W0, b0f, tid, 0);
    __syncthreads();
    phase<1, 0>(A, Wsl0, b1, accA, accB, 0, 0, lane, wave);
    layer0_half(A, gbase, W0, b0f, tid, 1);
    __syncthreads();
    phase<1, 1>(A, Wsl0, b1, accB, accA, 1, 0, lane, wave); // M1(h1)||E1(h0)
    __syncthreads();
    phase<1, 1>(A, Wsl1, b2, accA, accB, 0, 1, lane, wave); // M2(h0)||E1(h1)
    __syncthreads();
    phase<1, 1>(A, Wsl1, b2, accB, accA, 1, 0, lane, wave); // M2(h1)||E2(h0)
    __syncthreads();
    phase<1, 1>(A, Wsl2, b3, accA, accB, 0, 1, lane, wave); // M3(h0)||E2(h1)
    __syncthreads();
    phase<1, 1>(A, Wsl2, b3, accB, accA, 1, 0, lane, wave); // M3(h1)||E3(h0)
    __syncthreads();
    phase<0, 1>(A, Wsl2, b3, accA, accB, 0, 1, lane, wave); // E3(h1)
    __syncthreads();

    // final layer 256 -> 3 (16-padded, b4 in C-init); waves 0-1 cover the
    // 32 points; A is read-only here.
    if (wave < 2) {
        const int lr = lane & 15;
        const int h  = lane >> 4;
        const int p4 = wave * 16 + lr;
        f32x4 accf = (f32x4){b4[0], b4[1], b4[2], 0.f};
#pragma unroll
        for (int ks = 0; ks < 8; ++ks) {
            int kb = ks * 32 + h * 8;
            bf16x8v w = *(const bf16x8v*)(W4t + (ks * 64 + lane) * 8);
            bf16x8v a = *(const bf16x8v*)&A[p4 * NF + (kb ^ ((p4 & 7) << 3))];
            accf = __builtin_amdgcn_mfma_f32_16x16x32_bf16(w, a, accf, 0, 0, 0);
        }
        const int g = gbase + p4;
        if (h == 0 && g < NPTS) {
            lut[g] = (f32x4){accf[0], accf[1], accf[2], 0.f};
        }
    }
}

// ---------------------------------------------------------------------------
// pack: one 64B line per CELL; 24 bf16 (8 nodes x rgb) TIGHT in quads 0..2
// (48B), quad 3 pad. Value order: flat[i], i = ((di*2+dj)*2+dk)*3 + ch;
// word w = cvt_pk(flat[2w], flat[2w+1]), w = 0..11 across 3 u32x4.
// Apply then needs only THREE dwordx4 gathers (same line) per pixel.
// ---------------------------------------------------------------------------
__global__ void __launch_bounds__(256)
pack_kernel(const f32x4* __restrict__ lut, u32x4* __restrict__ lutC)
{
    const int cid = blockIdx.x * 256 + threadIdx.x;
    if (cid >= NCELL) return;
    const int ci = cid >> 10;
    const int cj = (cid >> 5) & 31;
    const int ck = cid & 31;

    float flat[24];
#pragma unroll
    for (int di = 0; di < 2; ++di)
#pragma unroll
        for (int dj = 0; dj < 2; ++dj) {
            const int g0 = ((ci + di) * G1 + (cj + dj)) * G1 + ck;
            f32x4 a = lut[g0], b = lut[g0 + 1];
            const int base = (di * 2 + dj) * 6;
            flat[base + 0] = a[0]; flat[base + 1] = a[1]; flat[base + 2] = a[2];
            flat[base + 3] = b[0]; flat[base + 4] = b[1]; flat[base + 5] = b[2];
        }

    u32 w[12];
#pragma unroll
    for (int i = 0; i < 12; ++i) w[i] = cvt_pk(flat[2 * i], flat[2 * i + 1]);

    lutC[cid * 4 + 0] = (u32x4){w[0], w[1], w[2],  w[3]};
    lutC[cid * 4 + 1] = (u32x4){w[4], w[5], w[6],  w[7]};
    lutC[cid * 4 + 2] = (u32x4){w[8], w[9], w[10], w[11]};
}

// ---------------------------------------------------------------------------
// apply: per pixel, trilinear interpolation from the 64B-cell LUT — 3 gathers
// hitting one cache line — + exact residual + exact clip. LUT 2 MB, L2-hot.
// Corner (di,dj) words: lo rgb then hi rgb across 3 consecutive words:
//   c00 -> w0,w1,w2 | c01 -> w3,w4,w5 | c10 -> w6,w7,w8 | c11 -> w9,w10,w11
// ---------------------------------------------------------------------------
__global__ void __launch_bounds__(256, 8)
apply_kernel(const float* __restrict__ x, const u32x4* __restrict__ lutC,
             float* __restrict__ out)
{
    const int idx = blockIdx.x * 256 + threadIdx.x; // 0 .. 4*HW-1
    const int img = idx >> 18;                      // HW = 2^18
    const int p   = idx & (HW - 1);
    const size_t base = (size_t)img * 3 * HW + p;

    const float x0 = x[base];
    const float x1 = x[base + HW];
    const float x2 = x[base + 2 * HW];

    const float u0 = x0 * (float)GSCALE, u1 = x1 * (float)GSCALE, u2 = x2 * (float)GSCALE;
    const int i = min((int)u0, GSCALE - 1);
    const int j = min((int)u1, GSCALE - 1);
    const int k = min((int)u2, GSCALE - 1);
    const float f0 = u0 - (float)i, f1 = u1 - (float)j, f2 = u2 - (float)k;

    const int cb = ((i * 32 + j) * 32 + k) * 4;
    const u32x4 Q0 = lutC[cb + 0];
    const u32x4 Q1 = lutC[cb + 1];
    const u32x4 Q2 = lutC[cb + 2];

    // k-lerp per corner from 3 words (wA = lo.r|lo.g, wB = lo.b|hi.r,
    // wC = hi.g|hi.b):
#define KLERP(wA, wB, wC, dr, dg, db) \
    float dr = bflo(wA) + f2 * (bfhi(wB) - bflo(wA)); \
    float dg = bfhi(wA) + f2 * (bflo(wC) - bfhi(wA)); \
    float db = bflo(wB) + f2 * (bfhi(wC) - bflo(wB));
    KLERP(Q0[0], Q0[1], Q0[2], a00r, a00g, a00b)   // corner di=0,dj=0
    KLERP(Q0[3], Q1[0], Q1[1], a01r, a01g, a01b)   // corner di=0,dj=1
    KLERP(Q1[2], Q1[3], Q2[0], a10r, a10g, a10b)   // corner di=1,dj=0
    KLERP(Q2[1], Q2[2], Q2[3], a11r, a11g, a11b)   // corner di=1,dj=1
#undef KLERP

    const float b0r = a00r + f1 * (a01r - a00r);
    const float b0g = a00g + f1 * (a01g - a00g);
    const float b0b = a00b + f1 * (a01b - a00b);
    const float b1r = a10r + f1 * (a11r - a10r);
    const float b1g = a10g + f1 * (a11g - a10g);
    const float b1b = a10b + f1 * (a11b - a10b);
    const float rr = b0r + f0 * (b1r - b0r);
    const float rg = b0g + f0 * (b1g - b0g);
    const float rb = b0b + f0 * (b1b - b0b);

    out[base]          = fminf(fmaxf(x0 + rr, 0.f), 1.f);
    out[base + HW]     = fminf(fmaxf(x1 + rg, 0.f), 1.f);
    out[base + 2 * HW] = fminf(fmaxf(x2 + rb, 0.f), 1.f);
}

extern "C" void kernel_launch(void* const* d_in, const int* in_sizes, int n_in,
                              void* d_out, int out_size, void* d_ws, size_t ws_size,
                              hipStream_t stream) {
    const float* x     = (const float*)d_in[0];
    const float* style = (const float*)d_in[1];
    const float* W0    = (const float*)d_in[2];
    const float* b0    = (const float*)d_in[3];
    const float* W1    = (const float*)d_in[4];
    const float* b1    = (const float*)d_in[5];
    const float* W2    = (const float*)d_in[6];
    const float* b2    = (const float*)d_in[7];
    const float* W3    = (const float*)d_in[8];
    const float* b3    = (const float*)d_in[9];
    const float* W4    = (const float*)d_in[10];
    const float* b4    = (const float*)d_in[11];
    float* out = (float*)d_out;

    // ws layout: Wt|W4t|b0f in first 512KB; lut f32 @512KB (575KB);
    // lutC @2MB (64B-aligned, 2MB). Total ~4MB.
    u16*   Wt   = (u16*)d_ws;
    u16*   W4t  = Wt + 3 * NF * NF;
    float* b0f  = (float*)(W4t + 16 * NF);
    f32x4* lut  = (f32x4*)((char*)d_ws + (512 * 1024));
    u32x4* lutC = (u32x4*)((char*)d_ws + (2 * 1024 * 1024));

    const int prep_threads = 3 * NF * NF + 16 * NF + NF;
    prep_kernel<<<(prep_threads + 255) / 256, 256, 0, stream>>>(
        W0, b0, style, W1, W2, W3, W4, Wt, W4t, b0f);

    build_kernel<<<NBUILD, 256, 0, stream>>>(
        W0, b1, b2, b3, b4, Wt, W4t, b0f, lut);

    pack_kernel<<<(NCELL + 255) / 256, 256, 0, stream>>>(lut, lutC);

    apply_kernel<<<(NIMG * HW) / 256, 256, 0, stream>>>(x, lutC, out);
}